// Round 9
// baseline (153.630 us; speedup 1.0000x reference)
//
#include <hip/hip_runtime.h>
#include <stdint.h>

#define I_DIM 2048
#define O_DIM 8192
#define T_TOK 512
#define NSTR  64
#define BK    64
#define NSTEP (I_DIM / BK)

#define TILE_B 32768  // bytes per (stripe,step): [hi 16KB | lo 16KB], pre-swizzled

// gemm8 LDS layout: A 8KB (32 rows x 128B, hi+lo) + B 16KB (64 rows, hi+lo) = 24KB
#define A_HI 0
#define A_LO 4096
#define B_OFF 8192
#define SMEM8 24576

// workspace layout (peak ~70.6MB)
#define WT_OFF   ((size_t)0)             // 64MB weight tiles
#define XC_OFF   ((size_t)67108864)      // 4MB xc f32
#define THR_OFF  ((size_t)71303168)      // 512KB thrs f32[64][2048]
#define PM_OFF   ((size_t)71827456)      // 2MB pm_part f32[64][8192]
#define PMB_OFF  ((size_t)73924608)      // 32KB pmb f32[8192]
#define CNT_OFF  ((size_t)73957376)      // 2KB counts i32[512]

typedef __attribute__((ext_vector_type(8))) short bf16x8;
typedef __attribute__((ext_vector_type(4))) float f32x4;
typedef __attribute__((ext_vector_type(4))) int i32x4;

__device__ __forceinline__ void gload16(const void* g, void* l) {
  __builtin_amdgcn_global_load_lds(
      (const __attribute__((address_space(1))) void*)g,
      (__attribute__((address_space(3))) void*)l, 16, 0, 0);
}

// k0: fused prep: xc = x - mu; thrs = thresholds*std; zero counts.
__global__ void cwic_prep(const float* __restrict__ x, const float* __restrict__ mu,
                          const float* __restrict__ thresholds,
                          const float* __restrict__ stdv, float* __restrict__ xc,
                          float* __restrict__ thrs, int* __restrict__ counts) {
  int idx = blockIdx.x * 256 + threadIdx.x;  // 262144 float4s of xc
  float4 xv = ((const float4*)x)[idx];
  float4 mv = ((const float4*)mu)[idx & 511];
  float4 r;
  r.x = xv.x - mv.x; r.y = xv.y - mv.y; r.z = xv.z - mv.z; r.w = xv.w - mv.w;
  ((float4*)xc)[idx] = r;
  if (idx < (NSTR * I_DIM) / 4) {  // 32768 float4s of thrs
    float4 t = ((const float4*)thresholds)[idx];
    float4 s = ((const float4*)stdv)[idx & 511];
    float4 ts;
    ts.x = t.x * s.x; ts.y = t.y * s.y; ts.z = t.z * s.z; ts.w = t.w * s.w;
    ((float4*)thrs)[idx] = ts;
  }
  if (idx < T_TOK) counts[idx] = 0;
}

// k1: weight split f32 -> bf16 hi/lo tiles (pre-swizzled LDS image) + post_mu partials.
__global__ __launch_bounds__(256) void cwic_wprep(const float* __restrict__ w,
                                                  const float* __restrict__ mu,
                                                  char* __restrict__ wt,
                                                  float* __restrict__ pm_part) {
  const int bp = blockIdx.x;  // 2048 = 64 stripes x 32 steps
  const int n = bp >> 5, step = bp & 31;
  const int tid = threadIdx.x;
  const int o = tid & 127, kh = tid >> 7;
  const float* wp = w + (size_t)(step * BK + kh * 32) * O_DIM + n * 128 + o;
  char* tb = wt + (size_t)bp * TILE_B;
  const int rowb = o * 128;
  const int swz = (o & 7) << 4;
  float pm = 0.0f;
  #pragma unroll
  for (int g = 0; g < 4; ++g) {
    unsigned hv[4], lv[4];
    unsigned hprev = 0, lprev = 0;
    #pragma unroll
    for (int e = 0; e < 8; ++e) {
      const int irow = step * BK + kh * 32 + g * 8 + e;
      float v = wp[(size_t)(g * 8 + e) * O_DIM];
      pm += mu[irow] * v;
      unsigned u = __builtin_bit_cast(unsigned, v);
      unsigned r = u + 0x7fffu + ((u >> 16) & 1u);
      unsigned short h = (unsigned short)(r >> 16);
      float hif = __builtin_bit_cast(float, r & 0xffff0000u);
      unsigned short lo = (unsigned short)(__builtin_bit_cast(unsigned, v - hif) >> 16);
      if ((e & 1) == 0) { hprev = h; lprev = lo; }
      else {
        hv[e >> 1] = hprev | (((unsigned)h) << 16);
        lv[e >> 1] = lprev | (((unsigned)lo) << 16);
      }
    }
    *(i32x4*)(tb + rowb + ((kh * 64 + g * 16) ^ swz)) = *(i32x4*)hv;
    *(i32x4*)(tb + 16384 + rowb + ((kh * 64 + g * 16) ^ swz)) = *(i32x4*)lv;
  }
  pm_part[(size_t)(step * 2 + kh) * O_DIM + n * 128 + o] = pm;
}

// k2: pmb[o] = bias[o] + sum_s pm_part[s][o] (fixed order, deterministic)
__global__ void cwic_pmb(const float* __restrict__ pm_part,
                         const float* __restrict__ bias, float* __restrict__ pmb) {
  int o = blockIdx.x * 256 + threadIdx.x;
  float s = bias[o];
  #pragma unroll 8
  for (int j = 0; j < 64; ++j) s += pm_part[(size_t)j * O_DIM + o];
  pmb[o] = s;
}

// k3: masked GEMM. Block = 32 tokens x 64 outputs (half-stripe), 4 waves
// (wave tile 16x32). A = (|xc|>thr ? xc : 0) staged cooperatively in LDS; B via
// global_load_lds from half of the pre-split tile image (contiguous 8KB per
// component; swizzle invariant since half*64 == 0 mod 8). 24KB LDS -> 6
// blocks/CU, grid 2048 -> ~24 waves/CU TLP. Static prefetch regs (rule #20).
__global__ __launch_bounds__(256, 6) void cwic_gemm8(
    const float* __restrict__ xc, const char* __restrict__ wt,
    const float* __restrict__ thrs, const float* __restrict__ pmb,
    float* __restrict__ y, int* __restrict__ counts) {
  extern __shared__ char smem[];
  const int b = blockIdx.x;
  // XCD swizzle: all 32 blocks of one stripe land on one XCD -> tiles L2-hot.
  const int nid = (b & 7) * 256 + (b >> 3);
  const int n = nid >> 5, half = (nid >> 4) & 1, th = nid & 15;
  const int trow0 = th * 32, ocol0 = n * 128 + half * 64;
  const int tid = threadIdx.x;
  const int lane = tid & 63, wid = tid >> 6;
  const int wr = wid >> 1, wc = wid & 1;
  const int l15 = lane & 15, l4 = lane >> 4;

  const int t_loc = tid >> 3, kq = tid & 7;  // A staging: token row (0..31), k-octet
  const float* xrow = xc + (size_t)(trow0 + t_loc) * I_DIM + kq * 8;
  const float* thg = thrs + (size_t)n * I_DIM + kq * 8;
  const char* wtb = wt + (size_t)(n * NSTEP) * TILE_B + half * 8192;

  f32x4 acc[2];
  acc[0] = (f32x4)(0.0f);
  acc[1] = (f32x4)(0.0f);

  float4 xA0, xA1, tA0, tA1;  // current-step prefetch regs (static names)
  float4 xB0, xB1, tB0, tB1;  // next-step prefetch regs
  int cnt = 0;

  // prefetch xc/thr for step 0
  xA0 = *(const float4*)(xrow);
  xA1 = *(const float4*)(xrow + 4);
  tA0 = *(const float4*)(thg);
  tA1 = *(const float4*)(thg + 4);

#define STEP8(STEP_I, XC0, XC1, TC0, TC1, XN0, XN1, TN0, TN1)                  \
  {                                                                            \
    const int step_ = (STEP_I);                                                \
    /* stage B(step): hi half-image (8KB) + lo half-image (8KB) */             \
    {                                                                          \
      const char* bs_ = wtb + (size_t)step_ * TILE_B + tid * 16;               \
      _Pragma("unroll") for (int j_ = 0; j_ < 2; ++j_) {                       \
        gload16(bs_ + j_ * 4096, smem + B_OFF + j_ * 4096 + tid * 16);         \
        gload16(bs_ + 16384 + j_ * 4096,                                       \
                smem + B_OFF + 8192 + j_ * 4096 + tid * 16);                   \
      }                                                                        \
    }                                                                          \
    /* prefetch xc/thr for step+1 into the OTHER static regs */                \
    {                                                                          \
      const int kk1_ = (step_ + 1 < NSTEP) ? (step_ + 1) * BK : step_ * BK;    \
      XN0 = *(const float4*)(xrow + kk1_);                                     \
      XN1 = *(const float4*)(xrow + kk1_ + 4);                                 \
      TN0 = *(const float4*)(thg + kk1_);                                      \
      TN1 = *(const float4*)(thg + kk1_ + 4);                                  \
    }                                                                          \
    /* A-build(step): mask+count + integer hi/lo split (verified bits) */      \
    {                                                                          \
      const float xs_[8] = {XC0.x, XC0.y, XC0.z, XC0.w, XC1.x, XC1.y, XC1.z, XC1.w}; \
      const float ts_[8] = {TC0.x, TC0.y, TC0.z, TC0.w, TC1.x, TC1.y, TC1.z, TC1.w}; \
      unsigned hv_[4], lv_[4];                                                 \
      unsigned hprev_ = 0, lprev_ = 0;                                         \
      _Pragma("unroll") for (int e_ = 0; e_ < 8; ++e_) {                       \
        bool keep_ = fabsf(xs_[e_]) > ts_[e_];                                 \
        cnt += keep_ ? 1 : 0;                                                  \
        float a_ = keep_ ? xs_[e_] : 0.0f;                                     \
        unsigned u_ = __builtin_bit_cast(unsigned, a_);                        \
        unsigned rr_ = u_ + 0x7fffu + ((u_ >> 16) & 1u);                       \
        unsigned short h_ = (unsigned short)(rr_ >> 16);                       \
        float hf_ = __builtin_bit_cast(float, rr_ & 0xffff0000u);              \
        unsigned short lo_ = (unsigned short)(__builtin_bit_cast(unsigned, a_ - hf_) >> 16); \
        if ((e_ & 1) == 0) { hprev_ = h_; lprev_ = lo_; }                      \
        else {                                                                 \
          hv_[e_ >> 1] = hprev_ | (((unsigned)h_) << 16);                      \
          lv_[e_ >> 1] = lprev_ | (((unsigned)lo_) << 16);                     \
        }                                                                      \
      }                                                                        \
      const int ad_ = t_loc * 128 + ((kq * 16) ^ ((t_loc & 7) << 4));          \
      *(i32x4*)(smem + A_HI + ad_) = *(i32x4*)hv_;                             \
      *(i32x4*)(smem + A_LO + ad_) = *(i32x4*)lv_;                             \
    }                                                                          \
    __syncthreads(); /* drains B gloads + A-writes visible */                  \
    __builtin_amdgcn_s_setprio(1);                                             \
    _Pragma("unroll") for (int s32_ = 0; s32_ < 2; ++s32_) {                   \
      const int r_ = wr * 16 + l15;                                            \
      const int ada_ = r_ * 128 + (((s32_ * 64) + l4 * 16) ^ ((r_ & 7) << 4)); \
      bf16x8 afh_ = *(const bf16x8*)(smem + A_HI + ada_);                      \
      bf16x8 afl_ = *(const bf16x8*)(smem + A_LO + ada_);                      \
      _Pragma("unroll") for (int ni_ = 0; ni_ < 2; ++ni_) {                    \
        const int o_ = wc * 32 + ni_ * 16 + l15;                               \
        const int adb_ = o_ * 128 + (((s32_ * 64) + l4 * 16) ^ ((o_ & 7) << 4)); \
        bf16x8 bh_ = *(const bf16x8*)(smem + B_OFF + adb_);                    \
        bf16x8 bl_ = *(const bf16x8*)(smem + B_OFF + 8192 + adb_);             \
        acc[ni_] = __builtin_amdgcn_mfma_f32_16x16x32_bf16(afh_, bh_, acc[ni_], 0, 0, 0); \
        acc[ni_] = __builtin_amdgcn_mfma_f32_16x16x32_bf16(afh_, bl_, acc[ni_], 0, 0, 0); \
        acc[ni_] = __builtin_amdgcn_mfma_f32_16x16x32_bf16(afl_, bh_, acc[ni_], 0, 0, 0); \
      }                                                                        \
    }                                                                          \
    __builtin_amdgcn_s_setprio(0);                                             \
    __syncthreads(); /* protect A/B LDS before next step's staging */          \
  }

  for (int sp = 0; sp < NSTEP; sp += 2) {
    STEP8(sp,     xA0, xA1, tA0, tA1, xB0, xB1, tB0, tB1);
    STEP8(sp + 1, xB0, xB1, tB0, tB1, xA0, xA1, tA0, tA1);
  }
#undef STEP8

  // ---- mask-count reduce: 8 threads (kq) share one token row; only the
  // half==0 blocks count (A-build is duplicated across the two col-halves) ----
  cnt += __shfl_xor(cnt, 1);
  cnt += __shfl_xor(cnt, 2);
  cnt += __shfl_xor(cnt, 4);
  if (kq == 0 && half == 0) atomicAdd(&counts[trow0 + t_loc], cnt);

  // ---- epilogue: y = acc + (post_mu + bias); C/D layout m89-verified ----
  #pragma unroll
  for (int ni = 0; ni < 2; ++ni) {
    const int o = ocol0 + wc * 32 + ni * 16 + l15;
    const float pv = pmb[o];
    const int row0 = trow0 + wr * 16 + l4 * 4;
    #pragma unroll
    for (int r = 0; r < 4; ++r) {
      y[(size_t)(row0 + r) * O_DIM + o] = acc[ni][r] + pv;
    }
  }
}

// k4: flops outputs. flops_sparse = 16777216 * cnt/(64*2048) = 128*cnt (exact).
__global__ void cwic_fin(const int* __restrict__ counts, float* __restrict__ outF) {
  int t = blockIdx.x * 256 + threadIdx.x;
  outF[t] = 16777216.0f;
  outF[T_TOK + t] = 128.0f * (float)counts[t];
}

extern "C" void kernel_launch(void* const* d_in, const int* in_sizes, int n_in,
                              void* d_out, int out_size, void* d_ws, size_t ws_size,
                              hipStream_t stream) {
  const float* x = (const float*)d_in[0];
  const float* w = (const float*)d_in[1];
  const float* bias = (const float*)d_in[2];
  const float* thresholds = (const float*)d_in[3];
  const float* mu = (const float*)d_in[4];
  const float* stdv = (const float*)d_in[5];
  float* y = (float*)d_out;

  char* ws = (char*)d_ws;
  char* wt = ws + WT_OFF;
  float* xc = (float*)(ws + XC_OFF);
  float* thrs = (float*)(ws + THR_OFF);
  float* pm_part = (float*)(ws + PM_OFF);
  float* pmb = (float*)(ws + PMB_OFF);
  int* counts = (int*)(ws + CNT_OFF);

  cwic_prep<<<1024, 256, 0, stream>>>(x, mu, thresholds, stdv, xc, thrs, counts);
  cwic_wprep<<<NSTR * NSTEP, 256, 0, stream>>>(w, mu, wt, pm_part);
  cwic_pmb<<<32, 256, 0, stream>>>(pm_part, bias, pmb);
  cwic_gemm8<<<2048, 256, SMEM8, stream>>>(xc, wt, thrs, pmb, y, counts);
  cwic_fin<<<2, 256, 0, stream>>>(counts, y + (size_t)T_TOK * O_DIM);
}

// Round 13
// 88.792 us; speedup vs baseline: 1.7302x; 1.7302x over previous
//
#include <hip/hip_runtime.h>
#include <hip/hip_bf16.h>
#include <stdint.h>

#define I_DIM 2048
#define O_DIM 8192
#define T_TOK 512
#define NSTR  64
#define BK    64
#define NSTEP (I_DIM / BK)

#define TILE_B 16384  // bytes per (stripe,step): B-hi only, pre-swizzled LDS image

// gemm9 LDS: A 8KB (32 rows x 128B, hi+lo) + B-hi 16KB = 24KB -> 6 blocks/CU
#define A_HI 0
#define A_LO 4096
#define B_OFF 8192
#define SMEM9 24576

// workspace layout (offsets kept from proven R8 map; WT now uses only 32MB)
#define WT_OFF   ((size_t)0)             // 32MB weight hi-tiles
#define XC_OFF   ((size_t)67108864)      // 4MB xc f32
#define THR_OFF  ((size_t)71303168)      // 512KB thrs f32[64][2048]
#define PM_OFF   ((size_t)71827456)      // 2MB pm_part f32[64][8192]
#define PMB_OFF  ((size_t)73924608)      // 32KB pmb f32[8192]
#define CNT_OFF  ((size_t)73957376)      // 2KB counts i32[512]

typedef __attribute__((ext_vector_type(8))) short bf16x8;
typedef __attribute__((ext_vector_type(4))) float f32x4;
typedef __attribute__((ext_vector_type(4))) int i32x4;

__device__ __forceinline__ void gload16(const void* g, void* l) {
  __builtin_amdgcn_global_load_lds(
      (const __attribute__((address_space(1))) void*)g,
      (__attribute__((address_space(3))) void*)l, 16, 0, 0);
}

// k0: fused prep: xc = x - mu; thrs = thresholds*std; zero counts.
__global__ void cwic_prep(const float* __restrict__ x, const float* __restrict__ mu,
                          const float* __restrict__ thresholds,
                          const float* __restrict__ stdv, float* __restrict__ xc,
                          float* __restrict__ thrs, int* __restrict__ counts) {
  int idx = blockIdx.x * 256 + threadIdx.x;  // 262144 float4s of xc
  float4 xv = ((const float4*)x)[idx];
  float4 mv = ((const float4*)mu)[idx & 511];
  float4 r;
  r.x = xv.x - mv.x; r.y = xv.y - mv.y; r.z = xv.z - mv.z; r.w = xv.w - mv.w;
  ((float4*)xc)[idx] = r;
  if (idx < (NSTR * I_DIM) / 4) {  // 32768 float4s of thrs
    float4 t = ((const float4*)thresholds)[idx];
    float4 s = ((const float4*)stdv)[idx & 511];
    float4 ts;
    ts.x = t.x * s.x; ts.y = t.y * s.y; ts.z = t.z * s.z; ts.w = t.w * s.w;
    ((float4*)thrs)[idx] = ts;
  }
  if (idx < T_TOK) counts[idx] = 0;
}

// k1: weight hi-split f32 -> bf16 RNE tiles (pre-swizzled LDS image) + post_mu
// partials. 2-product scheme: B-lo tiles deleted (y ~= (A_hi+A_lo) * B_hi).
__global__ __launch_bounds__(256) void cwic_wprep(const float* __restrict__ w,
                                                  const float* __restrict__ mu,
                                                  char* __restrict__ wt,
                                                  float* __restrict__ pm_part) {
  const int bp = blockIdx.x;  // 2048 = 64 stripes x 32 steps
  const int n = bp >> 5, step = bp & 31;
  const int tid = threadIdx.x;
  const int o = tid & 127, kh = tid >> 7;
  const float* wp = w + (size_t)(step * BK + kh * 32) * O_DIM + n * 128 + o;
  char* tb = wt + (size_t)bp * TILE_B;
  const int rowb = o * 128;
  const int swz = (o & 7) << 4;
  float pm = 0.0f;
  #pragma unroll
  for (int g = 0; g < 4; ++g) {
    unsigned hv[4];
    unsigned hprev = 0;
    #pragma unroll
    for (int e = 0; e < 8; ++e) {
      const int irow = step * BK + kh * 32 + g * 8 + e;
      float v = wp[(size_t)(g * 8 + e) * O_DIM];
      pm += mu[irow] * v;
      unsigned u = __builtin_bit_cast(unsigned, v);
      unsigned r = u + 0x7fffu + ((u >> 16) & 1u);   // RNE to bf16
      unsigned short h = (unsigned short)(r >> 16);
      if ((e & 1) == 0) hprev = h;
      else hv[e >> 1] = hprev | (((unsigned)h) << 16);
    }
    *(i32x4*)(tb + rowb + ((kh * 64 + g * 16) ^ swz)) = *(i32x4*)hv;
  }
  pm_part[(size_t)(step * 2 + kh) * O_DIM + n * 128 + o] = pm;
}

// k2: pmb[o] = bias[o] + sum_s pm_part[s][o] (fixed order, deterministic)
__global__ void cwic_pmb(const float* __restrict__ pm_part,
                         const float* __restrict__ bias, float* __restrict__ pmb) {
  int o = blockIdx.x * 256 + threadIdx.x;
  float s = bias[o];
  #pragma unroll 8
  for (int j = 0; j < 64; ++j) s += pm_part[(size_t)j * O_DIM + o];
  pmb[o] = s;
}

// k3: masked GEMM (R8 skeleton, 2-product). Block = 32 tokens x 128 outputs,
// 4 waves 2x2 (wave tile 16x64). A = (|xc|>thr ? xc : 0) split hi+lo via RNE
// bf16 casts, staged cooperatively in LDS; B-hi via global_load_lds. 24KB LDS
// -> 6 blocks/CU, grid 1024. Static prefetch regs (rule #20). 16 MFMA/step/wave.
__global__ __launch_bounds__(256, 6) void cwic_gemm9(
    const float* __restrict__ xc, const char* __restrict__ wt,
    const float* __restrict__ thrs, const float* __restrict__ pmb,
    float* __restrict__ y, int* __restrict__ counts) {
  extern __shared__ char smem[];
  const int b = blockIdx.x;
  // XCD swizzle: all 16 token-tiles of one stripe land on one XCD -> B L2-hot.
  const int nid = (b & 7) * 128 + (b >> 3);
  const int n = nid >> 4, th = nid & 15;
  const int trow0 = th * 32, ocol0 = n * 128;
  const int tid = threadIdx.x;
  const int lane = tid & 63, wid = tid >> 6;
  const int wr = wid >> 1, wc = wid & 1;
  const int l15 = lane & 15, l4 = lane >> 4;

  const int t_loc = tid >> 3, kq = tid & 7;  // A staging: token row (0..31), k-octet
  const float* xrow = xc + (size_t)(trow0 + t_loc) * I_DIM + kq * 8;
  const float* thg = thrs + (size_t)n * I_DIM + kq * 8;
  const char* wtb = wt + (size_t)(n * NSTEP) * TILE_B;

  f32x4 acc[4];
  #pragma unroll
  for (int ni = 0; ni < 4; ++ni) acc[ni] = (f32x4)(0.0f);

  float4 xA0, xA1, tA0, tA1;  // current-step prefetch regs (static names)
  float4 xB0, xB1, tB0, tB1;  // next-step prefetch regs
  int cnt = 0;

  // prefetch xc/thr for step 0
  xA0 = *(const float4*)(xrow);
  xA1 = *(const float4*)(xrow + 4);
  tA0 = *(const float4*)(thg);
  tA1 = *(const float4*)(thg + 4);

#define STEP9(STEP_I, XC0, XC1, TC0, TC1, XN0, XN1, TN0, TN1)                  \
  {                                                                            \
    const int step_ = (STEP_I);                                                \
    /* stage B-hi(step): 4 x global_load_lds(16B) from pre-swizzled tile */    \
    {                                                                          \
      const char* bs_ = wtb + (size_t)step_ * TILE_B + tid * 16;               \
      _Pragma("unroll") for (int j_ = 0; j_ < 4; ++j_)                         \
        gload16(bs_ + j_ * 4096, smem + B_OFF + j_ * 4096 + tid * 16);         \
    }                                                                          \
    /* prefetch xc/thr for step+1 into the OTHER static regs */                \
    {                                                                          \
      const int kk1_ = (step_ + 1 < NSTEP) ? (step_ + 1) * BK : step_ * BK;    \
      XN0 = *(const float4*)(xrow + kk1_);                                     \
      XN1 = *(const float4*)(xrow + kk1_ + 4);                                 \
      TN0 = *(const float4*)(thg + kk1_);                                      \
      TN1 = *(const float4*)(thg + kk1_ + 4);                                  \
    }                                                                          \
    /* A-build(step): mask+count + hi/lo split via RNE bf16 casts */           \
    {                                                                          \
      const float xs_[8] = {XC0.x, XC0.y, XC0.z, XC0.w, XC1.x, XC1.y, XC1.z, XC1.w}; \
      const float ts_[8] = {TC0.x, TC0.y, TC0.z, TC0.w, TC1.x, TC1.y, TC1.z, TC1.w}; \
      bf16x8 hv8_, lv8_;                                                       \
      _Pragma("unroll") for (int e_ = 0; e_ < 8; ++e_) {                       \
        bool keep_ = fabsf(xs_[e_]) > ts_[e_];                                 \
        cnt += keep_ ? 1 : 0;                                                  \
        float a_ = keep_ ? xs_[e_] : 0.0f;                                     \
        __hip_bfloat16 h_ = __float2bfloat16(a_);                              \
        float hf_ = __bfloat162float(h_);                                      \
        __hip_bfloat16 l_ = __float2bfloat16(a_ - hf_);                        \
        hv8_[e_] = __builtin_bit_cast(short, h_);                              \
        lv8_[e_] = __builtin_bit_cast(short, l_);                              \
      }                                                                        \
      const int ad_ = t_loc * 128 + ((kq * 16) ^ ((t_loc & 7) << 4));          \
      *(bf16x8*)(smem + A_HI + ad_) = hv8_;                                    \
      *(bf16x8*)(smem + A_LO + ad_) = lv8_;                                    \
    }                                                                          \
    __syncthreads(); /* drains B gloads + A-writes visible */                  \
    __builtin_amdgcn_s_setprio(1);                                             \
    _Pragma("unroll") for (int s32_ = 0; s32_ < 2; ++s32_) {                   \
      const int r_ = wr * 16 + l15;                                            \
      const int ada_ = r_ * 128 + (((s32_ * 64) + l4 * 16) ^ ((r_ & 7) << 4)); \
      bf16x8 afh_ = *(const bf16x8*)(smem + A_HI + ada_);                      \
      bf16x8 afl_ = *(const bf16x8*)(smem + A_LO + ada_);                      \
      _Pragma("unroll") for (int ni_ = 0; ni_ < 4; ++ni_) {                    \
        const int o_ = wc * 64 + ni_ * 16 + l15;                               \
        const int adb_ = o_ * 128 + (((s32_ * 64) + l4 * 16) ^ ((o_ & 7) << 4)); \
        bf16x8 bh_ = *(const bf16x8*)(smem + B_OFF + adb_);                    \
        acc[ni_] = __builtin_amdgcn_mfma_f32_16x16x32_bf16(afh_, bh_, acc[ni_], 0, 0, 0); \
        acc[ni_] = __builtin_amdgcn_mfma_f32_16x16x32_bf16(afl_, bh_, acc[ni_], 0, 0, 0); \
      }                                                                        \
    }                                                                          \
    __builtin_amdgcn_s_setprio(0);                                             \
    __syncthreads(); /* protect A/B LDS before next step's staging */          \
  }

  for (int sp = 0; sp < NSTEP; sp += 2) {
    STEP9(sp,     xA0, xA1, tA0, tA1, xB0, xB1, tB0, tB1);
    STEP9(sp + 1, xB0, xB1, tB0, tB1, xA0, xA1, tA0, tA1);
  }
#undef STEP9

  // ---- mask-count reduce: 8 threads (kq) share one token row ----
  cnt += __shfl_xor(cnt, 1);
  cnt += __shfl_xor(cnt, 2);
  cnt += __shfl_xor(cnt, 4);
  if (kq == 0) atomicAdd(&counts[trow0 + t_loc], cnt);

  // ---- epilogue: y = acc + (post_mu + bias); C/D layout m89-verified ----
  #pragma unroll
  for (int ni = 0; ni < 4; ++ni) {
    const int o = ocol0 + wc * 64 + ni * 16 + l15;
    const float pv = pmb[o];
    const int row0 = trow0 + wr * 16 + l4 * 4;
    #pragma unroll
    for (int r = 0; r < 4; ++r) {
      y[(size_t)(row0 + r) * O_DIM + o] = acc[ni][r] + pv;
    }
  }
}

// k4: flops outputs. flops_sparse = 16777216 * cnt/(64*2048) = 128*cnt (exact).
__global__ void cwic_fin(const int* __restrict__ counts, float* __restrict__ outF) {
  int t = blockIdx.x * 256 + threadIdx.x;
  outF[t] = 16777216.0f;
  outF[T_TOK + t] = 128.0f * (float)counts[t];
}

extern "C" void kernel_launch(void* const* d_in, const int* in_sizes, int n_in,
                              void* d_out, int out_size, void* d_ws, size_t ws_size,
                              hipStream_t stream) {
  const float* x = (const float*)d_in[0];
  const float* w = (const float*)d_in[1];
  const float* bias = (const float*)d_in[2];
  const float* thresholds = (const float*)d_in[3];
  const float* mu = (const float*)d_in[4];
  const float* stdv = (const float*)d_in[5];
  float* y = (float*)d_out;

  char* ws = (char*)d_ws;
  char* wt = ws + WT_OFF;
  float* xc = (float*)(ws + XC_OFF);
  float* thrs = (float*)(ws + THR_OFF);
  float* pm_part = (float*)(ws + PM_OFF);
  float* pmb = (float*)(ws + PMB_OFF);
  int* counts = (int*)(ws + CNT_OFF);

  cwic_prep<<<1024, 256, 0, stream>>>(x, mu, thresholds, stdv, xc, thrs, counts);
  cwic_wprep<<<NSTR * NSTEP, 256, 0, stream>>>(w, mu, wt, pm_part);
  cwic_pmb<<<32, 256, 0, stream>>>(pm_part, bias, pmb);
  cwic_gemm9<<<1024, 256, SMEM9, stream>>>(xc, wt, thrs, pmb, y, counts);
  cwic_fin<<<2, 256, 0, stream>>>(counts, y + (size_t)T_TOK * O_DIM);
}

// Round 14
// 88.265 us; speedup vs baseline: 1.7406x; 1.0060x over previous
//
#include <hip/hip_runtime.h>
#include <hip/hip_bf16.h>
#include <stdint.h>

#define I_DIM 2048
#define O_DIM 8192
#define T_TOK 512
#define NSTR  64
#define BK    64
#define NSTEP (I_DIM / BK)

#define TILE_B 16384  // bytes per (stripe,step): B-hi only, pre-swizzled LDS image

// gemm10 LDS: A 16KB (64 rows x 128B, hi+lo) + B-hi 16KB = 32KB -> 2 blocks/CU (grid-capped)
#define A_HI 0
#define A_LO 8192
#define B_OFF 16384
#define SMEM10 32768

// workspace layout
#define WT_OFF   ((size_t)0)             // 32MB weight hi-tiles
#define XC_OFF   ((size_t)67108864)      // 4MB xc f32
#define THR_OFF  ((size_t)71303168)      // 512KB thrs f32[64][2048]
#define PM_OFF   ((size_t)71827456)      // 2MB pm_part f32[64][8192]
#define PMB_OFF  ((size_t)73924608)      // 32KB pmb f32[8192]
#define CNT_OFF  ((size_t)73957376)      // 2KB counts i32[512]

typedef __attribute__((ext_vector_type(8))) short bf16x8;
typedef __attribute__((ext_vector_type(4))) float f32x4;
typedef __attribute__((ext_vector_type(4))) int i32x4;

__device__ __forceinline__ void gload16(const void* g, void* l) {
  __builtin_amdgcn_global_load_lds(
      (const __attribute__((address_space(1))) void*)g,
      (__attribute__((address_space(3))) void*)l, 16, 0, 0);
}

// k0: fused prep: xc = x - mu; thrs = thresholds*std; zero counts.
__global__ void cwic_prep(const float* __restrict__ x, const float* __restrict__ mu,
                          const float* __restrict__ thresholds,
                          const float* __restrict__ stdv, float* __restrict__ xc,
                          float* __restrict__ thrs, int* __restrict__ counts) {
  int idx = blockIdx.x * 256 + threadIdx.x;  // 262144 float4s of xc
  float4 xv = ((const float4*)x)[idx];
  float4 mv = ((const float4*)mu)[idx & 511];
  float4 r;
  r.x = xv.x - mv.x; r.y = xv.y - mv.y; r.z = xv.z - mv.z; r.w = xv.w - mv.w;
  ((float4*)xc)[idx] = r;
  if (idx < (NSTR * I_DIM) / 4) {  // 32768 float4s of thrs
    float4 t = ((const float4*)thresholds)[idx];
    float4 s = ((const float4*)stdv)[idx & 511];
    float4 ts;
    ts.x = t.x * s.x; ts.y = t.y * s.y; ts.z = t.z * s.z; ts.w = t.w * s.w;
    ((float4*)thrs)[idx] = ts;
  }
  if (idx < T_TOK) counts[idx] = 0;
}

// k1: weight hi-split f32 -> bf16 RNE tiles (pre-swizzled LDS image) + post_mu
// partials. 2-product scheme: y ~= (A_hi + A_lo) * B_hi.
__global__ __launch_bounds__(256) void cwic_wprep(const float* __restrict__ w,
                                                  const float* __restrict__ mu,
                                                  char* __restrict__ wt,
                                                  float* __restrict__ pm_part) {
  const int bp = blockIdx.x;  // 2048 = 64 stripes x 32 steps
  const int n = bp >> 5, step = bp & 31;
  const int tid = threadIdx.x;
  const int o = tid & 127, kh = tid >> 7;
  const float* wp = w + (size_t)(step * BK + kh * 32) * O_DIM + n * 128 + o;
  char* tb = wt + (size_t)bp * TILE_B;
  const int rowb = o * 128;
  const int swz = (o & 7) << 4;
  float pm = 0.0f;
  #pragma unroll
  for (int g = 0; g < 4; ++g) {
    unsigned hv[4];
    unsigned hprev = 0;
    #pragma unroll
    for (int e = 0; e < 8; ++e) {
      const int irow = step * BK + kh * 32 + g * 8 + e;
      float v = wp[(size_t)(g * 8 + e) * O_DIM];
      pm += mu[irow] * v;
      unsigned u = __builtin_bit_cast(unsigned, v);
      unsigned r = u + 0x7fffu + ((u >> 16) & 1u);   // RNE to bf16
      unsigned short h = (unsigned short)(r >> 16);
      if ((e & 1) == 0) hprev = h;
      else hv[e >> 1] = hprev | (((unsigned)h) << 16);
    }
    *(i32x4*)(tb + rowb + ((kh * 64 + g * 16) ^ swz)) = *(i32x4*)hv;
  }
  pm_part[(size_t)(step * 2 + kh) * O_DIM + n * 128 + o] = pm;
}

// k2: pmb[o] = bias[o] + sum_s pm_part[s][o] (fixed order, deterministic)
__global__ void cwic_pmb(const float* __restrict__ pm_part,
                         const float* __restrict__ bias, float* __restrict__ pmb) {
  int o = blockIdx.x * 256 + threadIdx.x;
  float s = bias[o];
  #pragma unroll 8
  for (int j = 0; j < 64; ++j) s += pm_part[(size_t)j * O_DIM + o];
  pmb[o] = s;
}

// k3: masked GEMM, LDS-traffic-optimized. Block = 64 tokens x 128 outputs, 4
// waves 2x2 (wave tile 32x64 -> 30.5 B LDS-read per MFLOP, 1.5x less than R13).
// A = (|xc|>thr ? xc : 0) hi/lo staged cooperatively (16 elem/thread); B-hi via
// global_load_lds. 2-product numerics bit-identical to R13 (absmax 0.03125).
__global__ __launch_bounds__(256, 2) void cwic_gemm10(
    const float* __restrict__ xc, const char* __restrict__ wt,
    const float* __restrict__ thrs, const float* __restrict__ pmb,
    float* __restrict__ y, int* __restrict__ counts) {
  extern __shared__ char smem[];
  const int b = blockIdx.x;
  // XCD swizzle: the 8 token-tiles of one stripe share an XCD -> B tiles L2-hot.
  const int nid = (b & 7) * 64 + (b >> 3);
  const int n = nid >> 3, tt = nid & 7;
  const int trow0 = tt * 64, ocol0 = n * 128;
  const int tid = threadIdx.x;
  const int lane = tid & 63, wid = tid >> 6;
  const int wr = wid >> 1, wc = wid & 1;
  const int l15 = lane & 15, l4 = lane >> 4;

  const int t_loc = tid >> 2, kq = tid & 3;  // A staging: token row (0..63), k-16-chunk
  const float* xrow = xc + (size_t)(trow0 + t_loc) * I_DIM + kq * 16;
  const float* thg = thrs + (size_t)n * I_DIM + kq * 16;
  const char* wtb = wt + (size_t)(n * NSTEP) * TILE_B;

  f32x4 acc[2][4];
  #pragma unroll
  for (int mi = 0; mi < 2; ++mi)
    #pragma unroll
    for (int ni = 0; ni < 4; ++ni) acc[mi][ni] = (f32x4)(0.0f);

  // static prefetch regs (rule #20): 4 xc + 4 thr float4 per buffer
  float4 xa0, xa1, xa2, xa3, ta0, ta1, ta2, ta3;
  float4 xb0, xb1, xb2, xb3, tb0, tb1, tb2, tb3;
  int cnt = 0;

  // prefetch xc/thr for step 0
  xa0 = *(const float4*)(xrow);     xa1 = *(const float4*)(xrow + 4);
  xa2 = *(const float4*)(xrow + 8); xa3 = *(const float4*)(xrow + 12);
  ta0 = *(const float4*)(thg);      ta1 = *(const float4*)(thg + 4);
  ta2 = *(const float4*)(thg + 8);  ta3 = *(const float4*)(thg + 12);

#define STEP10(STEP_I, X0, X1, X2, X3, T0, T1, T2, T3,                         \
               NX0, NX1, NX2, NX3, NT0, NT1, NT2, NT3)                         \
  {                                                                            \
    const int step_ = (STEP_I);                                                \
    /* stage B-hi(step): 4 x global_load_lds(16B) from pre-swizzled tile */    \
    {                                                                          \
      const char* bs_ = wtb + (size_t)step_ * TILE_B + tid * 16;               \
      _Pragma("unroll") for (int j_ = 0; j_ < 4; ++j_)                         \
        gload16(bs_ + j_ * 4096, smem + B_OFF + j_ * 4096 + tid * 16);         \
    }                                                                          \
    /* prefetch xc/thr for step+1 into the OTHER static regs */                \
    {                                                                          \
      const int kk1_ = (step_ + 1 < NSTEP) ? (step_ + 1) * BK : step_ * BK;    \
      NX0 = *(const float4*)(xrow + kk1_);      NX1 = *(const float4*)(xrow + kk1_ + 4); \
      NX2 = *(const float4*)(xrow + kk1_ + 8);  NX3 = *(const float4*)(xrow + kk1_ + 12); \
      NT0 = *(const float4*)(thg + kk1_);       NT1 = *(const float4*)(thg + kk1_ + 4);  \
      NT2 = *(const float4*)(thg + kk1_ + 8);   NT3 = *(const float4*)(thg + kk1_ + 12); \
    }                                                                          \
    /* A-build(step): 16 elems, mask+count + hi/lo split via RNE bf16 casts */ \
    {                                                                          \
      const float xs_[16] = {X0.x, X0.y, X0.z, X0.w, X1.x, X1.y, X1.z, X1.w,   \
                             X2.x, X2.y, X2.z, X2.w, X3.x, X3.y, X3.z, X3.w};  \
      const float ts_[16] = {T0.x, T0.y, T0.z, T0.w, T1.x, T1.y, T1.z, T1.w,   \
                             T2.x, T2.y, T2.z, T2.w, T3.x, T3.y, T3.z, T3.w};  \
      const int rowb_ = t_loc * 128;                                           \
      const int swz_ = (t_loc & 7) << 4;                                       \
      _Pragma("unroll") for (int g_ = 0; g_ < 2; ++g_) {                       \
        bf16x8 hv8_, lv8_;                                                     \
        _Pragma("unroll") for (int e_ = 0; e_ < 8; ++e_) {                     \
          const float xv_ = xs_[g_ * 8 + e_], tv_ = ts_[g_ * 8 + e_];          \
          bool keep_ = fabsf(xv_) > tv_;                                       \
          cnt += keep_ ? 1 : 0;                                                \
          float a_ = keep_ ? xv_ : 0.0f;                                       \
          __hip_bfloat16 h_ = __float2bfloat16(a_);                            \
          float hf_ = __bfloat162float(h_);                                    \
          __hip_bfloat16 l_ = __float2bfloat16(a_ - hf_);                      \
          hv8_[e_] = __builtin_bit_cast(short, h_);                            \
          lv8_[e_] = __builtin_bit_cast(short, l_);                            \
        }                                                                      \
        const int ad_ = rowb_ + (((kq * 32) + g_ * 16) ^ swz_);                \
        *(bf16x8*)(smem + A_HI + ad_) = hv8_;                                  \
        *(bf16x8*)(smem + A_LO + ad_) = lv8_;                                  \
      }                                                                        \
    }                                                                          \
    __syncthreads(); /* drains B gloads + A-writes visible */                  \
    __builtin_amdgcn_s_setprio(1);                                             \
    _Pragma("unroll") for (int s32_ = 0; s32_ < 2; ++s32_) {                   \
      bf16x8 afh_[2], afl_[2];                                                 \
      _Pragma("unroll") for (int mi_ = 0; mi_ < 2; ++mi_) {                    \
        const int r_ = wr * 32 + mi_ * 16 + l15;                               \
        const int ada_ = r_ * 128 + (((s32_ * 64) + l4 * 16) ^ ((r_ & 7) << 4)); \
        afh_[mi_] = *(const bf16x8*)(smem + A_HI + ada_);                      \
        afl_[mi_] = *(const bf16x8*)(smem + A_LO + ada_);                      \
      }                                                                        \
      _Pragma("unroll") for (int ni_ = 0; ni_ < 4; ++ni_) {                    \
        const int o_ = wc * 64 + ni_ * 16 + l15;                               \
        const int adb_ = o_ * 128 + (((s32_ * 64) + l4 * 16) ^ ((o_ & 7) << 4)); \
        bf16x8 bh_ = *(const bf16x8*)(smem + B_OFF + adb_);                    \
        _Pragma("unroll") for (int mi_ = 0; mi_ < 2; ++mi_) {                  \
          acc[mi_][ni_] = __builtin_amdgcn_mfma_f32_16x16x32_bf16(afh_[mi_], bh_, acc[mi_][ni_], 0, 0, 0); \
          acc[mi_][ni_] = __builtin_amdgcn_mfma_f32_16x16x32_bf16(afl_[mi_], bh_, acc[mi_][ni_], 0, 0, 0); \
        }                                                                      \
      }                                                                        \
    }                                                                          \
    __builtin_amdgcn_s_setprio(0);                                             \
    __syncthreads(); /* protect A/B LDS before next step's staging */          \
  }

  for (int sp = 0; sp < NSTEP; sp += 2) {
    STEP10(sp,     xa0, xa1, xa2, xa3, ta0, ta1, ta2, ta3,
                   xb0, xb1, xb2, xb3, tb0, tb1, tb2, tb3);
    STEP10(sp + 1, xb0, xb1, xb2, xb3, tb0, tb1, tb2, tb3,
                   xa0, xa1, xa2, xa3, ta0, ta1, ta2, ta3);
  }
#undef STEP10

  // ---- mask-count reduce: 4 threads (kq) share one token row ----
  cnt += __shfl_xor(cnt, 1);
  cnt += __shfl_xor(cnt, 2);
  if (kq == 0) atomicAdd(&counts[trow0 + t_loc], cnt);

  // ---- epilogue: y = acc + (post_mu + bias); C/D layout m89-verified ----
  #pragma unroll
  for (int ni = 0; ni < 4; ++ni) {
    const int o = ocol0 + wc * 64 + ni * 16 + l15;
    const float pv = pmb[o];
    #pragma unroll
    for (int mi = 0; mi < 2; ++mi) {
      const int row0 = trow0 + wr * 32 + mi * 16 + l4 * 4;
      #pragma unroll
      for (int r = 0; r < 4; ++r) {
        y[(size_t)(row0 + r) * O_DIM + o] = acc[mi][ni][r] + pv;
      }
    }
  }
}

// k4: flops outputs. flops_sparse = 16777216 * cnt/(64*2048) = 128*cnt (exact).
__global__ void cwic_fin(const int* __restrict__ counts, float* __restrict__ outF) {
  int t = blockIdx.x * 256 + threadIdx.x;
  outF[t] = 16777216.0f;
  outF[T_TOK + t] = 128.0f * (float)counts[t];
}

extern "C" void kernel_launch(void* const* d_in, const int* in_sizes, int n_in,
                              void* d_out, int out_size, void* d_ws, size_t ws_size,
                              hipStream_t stream) {
  const float* x = (const float*)d_in[0];
  const float* w = (const float*)d_in[1];
  const float* bias = (const float*)d_in[2];
  const float* thresholds = (const float*)d_in[3];
  const float* mu = (const float*)d_in[4];
  const float* stdv = (const float*)d_in[5];
  float* y = (float*)d_out;

  char* ws = (char*)d_ws;
  char* wt = ws + WT_OFF;
  float* xc = (float*)(ws + XC_OFF);
  float* thrs = (float*)(ws + THR_OFF);
  float* pm_part = (float*)(ws + PM_OFF);
  float* pmb = (float*)(ws + PMB_OFF);
  int* counts = (int*)(ws + CNT_OFF);

  cwic_prep<<<1024, 256, 0, stream>>>(x, mu, thresholds, stdv, xc, thrs, counts);
  cwic_wprep<<<NSTR * NSTEP, 256, 0, stream>>>(w, mu, wt, pm_part);
  cwic_pmb<<<32, 256, 0, stream>>>(pm_part, bias, pmb);
  cwic_gemm10<<<512, 256, SMEM10, stream>>>(xc, wt, thrs, pmb, y, counts);
  cwic_fin<<<2, 256, 0, stream>>>(counts, y + (size_t)T_TOK * O_DIM);
}